// Round 6
// baseline (215.040 us; speedup 1.0000x reference)
//
#include <hip/hip_runtime.h>

// VQ-VAE VectorQuantizer forward for MI355X (gfx950) — MFMA-filtered argmin.
// z_e: (64, 256, 32, 32) fp32; codebook: (512, 256) fp32.
// Outputs concatenated in d_out (float32):
//   [0, 16777216)        z_q_st  (== z_e + (z_q - z_e), fp32 elementwise)
//   [16777216]           commitment_loss
//   [16777217]           codebook_loss (same value)
//   [16777218, +65536)   indices (as float)
//
// Index semantics: bitwise emulation of numpy-fp32
//   d = sum(z**2,axis=1,keepdims=True) + sum(e**2,axis=1) - 2*matmul(z, e.T)
//   idx = argmin(d, axis=1)   (first occurrence on exact fp32 ties)
// Strategy: bf16(hi)-only MFMA computes approximate scores (|err| << EPS/2);
// per-row candidates within EPS of the approx min are re-scored with the
// bitwise-exact sequential fp32 FMA chain (ascending d) and reduced with
// (d asc, tie -> lower k). Overflowing rows fall back to exact scan of all K.
// Structure: argmin kernel reads z once (fused norm+convert); a separate
// streaming kernel does gather/ST/loss at HBM rate.

typedef __attribute__((ext_vector_type(8))) short short8v;
typedef __attribute__((ext_vector_type(4))) float float4v;
typedef unsigned short ushort_t;

namespace {
constexpr int K = 512;
constexpr int D = 256;
constexpr int HW = 1024;          // 32*32
constexpr int NROWS = 65536;      // 64*HW
constexpr int CHW = D * HW;       // 262144

constexpr int ZQ_SIZE = 64 * CHW; // 16777216
constexpr int LOSS0_OFF = ZQ_SIZE;
constexpr int LOSS1_OFF = ZQ_SIZE + 1;
constexpr int IDX_OFF = ZQ_SIZE + 2;

// workspace layout (float offsets); total ~522 KB
constexpr int WS_EH_FLOATS = (K * D) / 2;  // eH bf16[512][256] = 65536 floats
constexpr int WS_B = WS_EH_FLOATS;         // ||e_k||^2 (numpy pairwise), 512
constexpr int WS_KIDX = WS_B + K;          // best index per row (int), 65536
constexpr int WS_PART = WS_KIDX + NROWS;   // per-block loss partials, 2048

constexpr int NBLK_A = NROWS / 32;         // 2048 argmin blocks (32 rows)
constexpr int NBLK_G = 2048;               // 64 img x 4 hw-quarter x 8 c-group

constexpr float EPS_CAND = 3.0e-3f;        // candidate window (>> 2*max err)
constexpr int MAXC = 16;                   // candidate slots per row
}  // namespace

__device__ __forceinline__ ushort_t bf16_rne(float f) {
    unsigned u = __float_as_uint(f);
    u += 0x7fffu + ((u >> 16) & 1u);   // round-to-nearest-even (no NaN in data)
    return (ushort_t)(u >> 16);
}

// ---------------------------------------------------------------------------
// Kernel 1: eH[k][d] = bf16(cb[k][d]); B[k] = ||e_k||^2 in numpy pairwise
// order: pw(x,256)=pw(x,128)+pw(x+128,128); pw(x,128): 8 accums x 16 strided
// adds, then ((r0+r1)+(r2+r3))+((r4+r5)+(r6+r7)).
__global__ void vq_prep(const float* __restrict__ cb, float* __restrict__ ws) {
    const int k = blockIdx.x;
    const int t = threadIdx.x;  // 0..255 == d
    ushort_t* eh = (ushort_t*)ws;
    eh[(size_t)k * D + t] = bf16_rne(cb[k * D + t]);
    __shared__ float r16[16];
    if (t < 16) {
#pragma clang fp contract(off)
        const float* x = cb + k * D + (t >> 3) * 128;
        const int j = t & 7;
        float v = x[j];
        float r = v * v;
        for (int i = 1; i < 16; ++i) {
            float w = x[8 * i + j];
            r += w * w;
        }
        r16[t] = r;
    }
    __syncthreads();
    if (t == 0) {
#pragma clang fp contract(off)
        float lo = ((r16[0] + r16[1]) + (r16[2] + r16[3])) +
                   ((r16[4] + r16[5]) + (r16[6] + r16[7]));
        float hi = ((r16[8] + r16[9]) + (r16[10] + r16[11])) +
                   ((r16[12] + r16[13]) + (r16[14] + r16[15]));
        ws[WS_B + k] = lo + hi;
    }
}

// ---------------------------------------------------------------------------
// Kernel 2: argmin. Per 32-row block (~24 KB LDS, 6 blocks/CU):
//   ONE fused pass over z: numpy-pairwise A chains + bf16-hi -> LDS;
//   MFMA approx scores (4 waves x 128 codes x 32 rows, hi term only);
//   per-row approx min + candidate collection (<= min+EPS);
//   exact fp32-chain re-score of candidates (sparse global z reads);
//   index write (float to out, int to ws for the gather kernel).
__global__ __launch_bounds__(256, 6) void vq_argmin2(
    const float* __restrict__ z_e, const float* __restrict__ cb,
    const ushort_t* __restrict__ eh, const float* __restrict__ Bv,
    int* __restrict__ wsidx, float* __restrict__ out) {
    __shared__ __align__(16) ushort_t zh[32][264];    // 16.9 KB bf16 hi, padded
    __shared__ float lds_B[K];                        // 2 KB ||e_k||^2
    __shared__ float scr[32][17];                     // 2.2 KB pairwise accums
    __shared__ int cand[32][MAXC];                    // 2 KB candidate codes
    __shared__ float lds_A[32];
    __shared__ float wmin[4][32];
    __shared__ float rmin[32];
    __shared__ int cnt[32];

    const int t = threadIdx.x;
    const int row0 = blockIdx.x * 32;
    const int b = row0 >> 10;
    const int hw0 = row0 & 1023;
    const float* zbase = z_e + (size_t)b * CHW + hw0;

    // ---- B staging
    lds_B[t] = Bv[t];
    lds_B[t + 256] = Bv[t + 256];

    // ---- fused: A pairwise chains + bf16-hi conversion (single z read).
    // thread (row=t&31, q=t>>5): half=q>>2, j0=(q&3)*2; channels cbase+8i+j0{,+1}.
    {
        const int row = t & 31;
        const int q = t >> 5;
        const int half = q >> 2;
        const int j0 = (q & 3) * 2;
        const int cbase = half * 128;
        const float* zp = zbase + row;
        float r0, r1;
        {
#pragma clang fp contract(off)
            const int c0 = cbase + j0;
            float w0 = zp[(size_t)c0 * HW];
            float w1 = zp[(size_t)(c0 + 1) * HW];
            r0 = w0 * w0;
            r1 = w1 * w1;
            *reinterpret_cast<unsigned*>(&zh[row][c0]) =
                (unsigned)bf16_rne(w0) | ((unsigned)bf16_rne(w1) << 16);
            for (int i = 1; i < 16; ++i) {
                const int c = cbase + 8 * i + j0;
                float u0 = zp[(size_t)c * HW];
                float u1 = zp[(size_t)(c + 1) * HW];
                r0 += u0 * u0;
                r1 += u1 * u1;
                *reinterpret_cast<unsigned*>(&zh[row][c]) =
                    (unsigned)bf16_rne(u0) | ((unsigned)bf16_rne(u1) << 16);
            }
        }
        scr[row][half * 8 + j0] = r0;
        scr[row][half * 8 + j0 + 1] = r1;
    }
    __syncthreads();
    if (t < 32) {
#pragma clang fp contract(off)
        const float* r = scr[t];
        float lo = ((r[0] + r[1]) + (r[2] + r[3])) + ((r[4] + r[5]) + (r[6] + r[7]));
        float hi = ((r[8] + r[9]) + (r[10] + r[11])) + ((r[12] + r[13]) + (r[14] + r[15]));
        lds_A[t] = lo + hi;
    }

    // ---- MFMA main loop: wave w owns codes [w*128, w*128+128), all 32 rows.
    // A = E (codes = M), B = Z-hi (rows = N). hi term only.
    // C frag (m89-verified): col = lane&15 = z-row; row = 4*(lane>>4)+reg = code.
    const int lane = t & 63;
    const int w = t >> 6;
    const int wc0 = w * 128;
    const int l15 = lane & 15;
    const int kg = lane >> 4;

    float4v acc[8][2];
#pragma unroll
    for (int c = 0; c < 8; ++c)
#pragma unroll
        for (int rt = 0; rt < 2; ++rt) acc[c][rt] = (float4v)0.f;

    const ushort_t* ehp = eh + (size_t)(wc0 + l15) * D + 8 * kg;

#pragma unroll 4
    for (int d0 = 0; d0 < D; d0 += 32) {
        const short8v bh0 = *reinterpret_cast<const short8v*>(&zh[l15][d0 + 8 * kg]);
        const short8v bh1 = *reinterpret_cast<const short8v*>(&zh[16 + l15][d0 + 8 * kg]);
#pragma unroll
        for (int c = 0; c < 8; ++c) {
            const short8v a = *reinterpret_cast<const short8v*>(ehp + c * 16 * D + d0);
            acc[c][0] = __builtin_amdgcn_mfma_f32_16x16x32_bf16(a, bh0, acc[c][0], 0, 0, 0);
            acc[c][1] = __builtin_amdgcn_mfma_f32_16x16x32_bf16(a, bh1, acc[c][1], 0, 0, 0);
        }
    }
    __syncthreads();  // lds_A ready for all; zh stable until cand phase done

    // ---- approx scores + per-row min
    float lmin0 = 3.0e38f, lmin1 = 3.0e38f;
#pragma unroll
    for (int c = 0; c < 8; ++c)
#pragma unroll
        for (int rt = 0; rt < 2; ++rt)
#pragma unroll
            for (int r = 0; r < 4; ++r) {
                const int code = wc0 + 16 * c + 4 * kg + r;
                const int row = rt * 16 + l15;
                float s = (lds_A[row] + lds_B[code]) - 2.0f * acc[c][rt][r];
                acc[c][rt][r] = s;
                if (rt == 0) lmin0 = fminf(lmin0, s);
                else lmin1 = fminf(lmin1, s);
            }
    lmin0 = fminf(lmin0, __shfl_xor(lmin0, 16));
    lmin0 = fminf(lmin0, __shfl_xor(lmin0, 32));
    lmin1 = fminf(lmin1, __shfl_xor(lmin1, 16));
    lmin1 = fminf(lmin1, __shfl_xor(lmin1, 32));
    if (lane < 16) {
        wmin[w][l15] = lmin0;
        wmin[w][16 + l15] = lmin1;
    }
    __syncthreads();
    if (t < 32) {
        rmin[t] = fminf(fminf(wmin[0][t], wmin[1][t]), fminf(wmin[2][t], wmin[3][t]));
        cnt[t] = 0;
    }
    __syncthreads();

    // ---- candidate collection (any possible exact winner is within EPS)
#pragma unroll
    for (int c = 0; c < 8; ++c)
#pragma unroll
        for (int rt = 0; rt < 2; ++rt) {
            const int row = rt * 16 + l15;
            const float thr = rmin[row] + EPS_CAND;
#pragma unroll
            for (int r = 0; r < 4; ++r) {
                if (acc[c][rt][r] <= thr) {
                    const int code = wc0 + 16 * c + 4 * kg + r;
                    int slot = atomicAdd(&cnt[row], 1);
                    if (slot < MAXC) cand[row][slot] = code;
                }
            }
        }
    __syncthreads();

    // ---- exact pass: bitwise numpy-fp32 chain for rows with >=2 candidates.
    // zh buffer is dead now; alias reduction arrays onto it.
    float* ed = reinterpret_cast<float*>(&zh[0][0]);  // [8][32]
    int* ek = reinterpret_cast<int*>(ed + 256);       // [8][32]
    {
        const int row = t & 31;
        const int ct = t >> 5;  // 0..7 candidate-threads per row
        const float* zp = zbase + row;
        const int n = cnt[row];
        float bd = 3.0e38f;
        int bk = 0x7fffffff;
        if (n == 1) {
            if (ct == 0) {
                bd = -3.0e38f;
                bk = cand[row][0];
            }
        } else {
            const bool full = (n > MAXC);  // overflow: exact-scan all codes
            const int lim = full ? K : n;
            for (int s = ct; s < lim; s += 8) {
                const int k = full ? s : cand[row][s];
                const float* ep = cb + (size_t)k * D;
                float a = 0.f;
#pragma unroll 8
                for (int c = 0; c < D; ++c) a = fmaf(zp[(size_t)c * HW], ep[c], a);
                float dv;
                {
#pragma clang fp contract(off)
                    float t1 = lds_A[row] + lds_B[k];
                    dv = t1 - 2.0f * a;
                }
                if (dv < bd || (dv == bd && k < bk)) {
                    bd = dv;
                    bk = k;
                }
            }
        }
        ed[t] = bd;
        ek[t] = bk;
    }
    __syncthreads();
    if (t < 32) {
        float bd = ed[t];
        int bk = ek[t];
#pragma unroll
        for (int q = 1; q < 8; ++q) {
            float od = ed[q * 32 + t];
            int ok = ek[q * 32 + t];
            if (od < bd || (od == bd && ok < bk)) {
                bd = od;
                bk = ok;
            }
        }
        wsidx[row0 + t] = bk;
        out[IDX_OFF + row0 + t] = (float)bk;
    }
}

// ---------------------------------------------------------------------------
// Kernel 3: streaming gather / straight-through write / loss partials.
// Block: 256 threads = 4 waves; block covers (image b, 256 hw, 32 channels).
// Thread: 4 consecutive hw (float4), 8 channels; codebook rows are 4
// sequential L1-friendly streams. Zero LDS except 16 B -> max occupancy.
__global__ __launch_bounds__(256, 8) void vq_gather2(
    const float* __restrict__ z_e, const float* __restrict__ cb,
    const int* __restrict__ wsidx, float* __restrict__ part,
    float* __restrict__ out) {
    __shared__ float wpart[4];
    const int t = threadIdx.x;
    const int blk = blockIdx.x;
    const int cg = blk & 7;        // channel group (32 c)
    const int q = (blk >> 3) & 3;  // hw quarter (256 hw)
    const int b = blk >> 5;        // image
    const int lane = t & 63;
    const int csub = t >> 6;       // 0..3 (wave id)
    const int hw = q * 256 + lane * 4;

    const int4 kk = *reinterpret_cast<const int4*>(&wsidx[b * HW + hw]);
    const float* e0 = cb + (size_t)kk.x * D;
    const float* e1 = cb + (size_t)kk.y * D;
    const float* e2 = cb + (size_t)kk.z * D;
    const float* e3 = cb + (size_t)kk.w * D;
    const size_t zoff = (size_t)b * CHW + hw;

    float accum = 0.f;
#pragma unroll 2
    for (int i = 0; i < 8; ++i) {
        const int c = cg * 32 + csub * 8 + i;
        const size_t off = zoff + (size_t)c * HW;
        const float4 z4 = *reinterpret_cast<const float4*>(&z_e[off]);
        const float ex = e0[c], ey = e1[c], ez = e2[c], ew = e3[c];
        float4 o4;
        o4.x = z4.x + (ex - z4.x);
        o4.y = z4.y + (ey - z4.y);
        o4.z = z4.z + (ez - z4.z);
        o4.w = z4.w + (ew - z4.w);
        *reinterpret_cast<float4*>(&out[off]) = o4;
        accum = fmaf(z4.x - ex, z4.x - ex, accum);
        accum = fmaf(z4.y - ey, z4.y - ey, accum);
        accum = fmaf(z4.z - ez, z4.z - ez, accum);
        accum = fmaf(z4.w - ew, z4.w - ew, accum);
    }
#pragma unroll
    for (int m = 1; m < 64; m <<= 1) accum += __shfl_xor(accum, m);
    if (lane == 0) wpart[csub] = accum;
    __syncthreads();
    if (t == 0) part[blk] = (wpart[0] + wpart[1]) + (wpart[2] + wpart[3]);
}

// ---------------------------------------------------------------------------
// Kernel 4: final loss reduction (2048 partials, fp64, deterministic).
__global__ void vq_finish(const float* __restrict__ part, float* __restrict__ out) {
    const int t = threadIdx.x;  // 256 threads
    double s = 0.0;
#pragma unroll
    for (int i = 0; i < 8; ++i) s += (double)part[t + 256 * i];
#pragma unroll
    for (int m = 1; m < 64; m <<= 1) s += __shfl_xor(s, m);
    __shared__ double wsum[4];
    if ((t & 63) == 0) wsum[t >> 6] = s;
    __syncthreads();
    if (t == 0) {
        double mean = (wsum[0] + wsum[1] + wsum[2] + wsum[3]) / (double)ZQ_SIZE;
        out[LOSS0_OFF] = (float)mean;
        out[LOSS1_OFF] = (float)mean;
    }
}

// ---------------------------------------------------------------------------
extern "C" void kernel_launch(void* const* d_in, const int* in_sizes, int n_in,
                              void* d_out, int out_size, void* d_ws, size_t ws_size,
                              hipStream_t stream) {
    const float* z_e = (const float*)d_in[0];
    const float* cb = (const float*)d_in[1];
    float* out = (float*)d_out;
    float* ws = (float*)d_ws;

    const ushort_t* eh = (const ushort_t*)ws;
    float* Bv = ws + WS_B;
    int* wsidx = (int*)(ws + WS_KIDX);
    float* part = ws + WS_PART;

    vq_prep<<<K, D, 0, stream>>>(cb, ws);
    vq_argmin2<<<NBLK_A, 256, 0, stream>>>(z_e, cb, eh, Bv, wsidx, out);
    vq_gather2<<<NBLK_G, 256, 0, stream>>>(z_e, cb, wsidx, part, out);
    vq_finish<<<1, 256, 0, stream>>>(part, out);
}

// Round 7
// 148.355 us; speedup vs baseline: 1.4495x; 1.4495x over previous
//
#include <hip/hip_runtime.h>

// VQ-VAE VectorQuantizer forward for MI355X (gfx950) — MFMA-filtered argmin.
// z_e: (64, 256, 32, 32) fp32; codebook: (512, 256) fp32.
// Outputs concatenated in d_out (float32):
//   [0, 16777216)        z_q_st  (== z_e + (z_q - z_e), fp32 elementwise)
//   [16777216]           commitment_loss
//   [16777217]           codebook_loss (same value)
//   [16777218, +65536)   indices (as float)
//
// Index semantics: bitwise emulation of numpy-fp32
//   d = sum(z**2,axis=1,keepdims=True) + sum(e**2,axis=1) - 2*matmul(z, e.T)
//   idx = argmin(d, axis=1)   (first occurrence on exact fp32 ties)
// Strategy: bf16(hi)-only MFMA computes approximate scores (|err| << EPS/2);
// per-row candidates within EPS of the approx min are re-scored with the
// bitwise-exact sequential fp32 FMA chain (ascending d) and reduced with
// (d asc, tie -> lower k). Overflowing rows fall back to exact scan of all K.
//
// NOTE on __launch_bounds__: the MFMA accumulator needs 64 regs; caps
// tighter than (256,4) force the compiler to spill acc to scratch
// (round-6 rocprof: 322 MB HBM writes of pure spill traffic). Keep >= 128
// regs/wave budget: (256,4).

typedef __attribute__((ext_vector_type(8))) short short8v;
typedef __attribute__((ext_vector_type(4))) float float4v;
typedef unsigned short ushort_t;

namespace {
constexpr int K = 512;
constexpr int D = 256;
constexpr int HW = 1024;          // 32*32
constexpr int NROWS = 65536;      // 64*HW
constexpr int CHW = D * HW;       // 262144

constexpr int ZQ_SIZE = 64 * CHW; // 16777216
constexpr int LOSS0_OFF = ZQ_SIZE;
constexpr int LOSS1_OFF = ZQ_SIZE + 1;
constexpr int IDX_OFF = ZQ_SIZE + 2;

// workspace layout (float offsets); total ~522 KB
constexpr int WS_EH_FLOATS = (K * D) / 2;  // eH bf16[512][256] = 65536 floats
constexpr int WS_B = WS_EH_FLOATS;         // ||e_k||^2 (numpy pairwise), 512
constexpr int WS_KIDX = WS_B + K;          // best index per row (int), 65536
constexpr int WS_PART = WS_KIDX + NROWS;   // per-block loss partials, 2048

constexpr int NBLK_A = NROWS / 32;         // 2048 argmin blocks (32 rows)
constexpr int NBLK_G = 2048;               // 64 img x 4 hw-quarter x 8 c-group

constexpr float EPS_CAND = 3.0e-3f;        // candidate window (>> 2*max err)
constexpr int MAXC = 16;                   // candidate slots per row
}  // namespace

__device__ __forceinline__ ushort_t bf16_rne(float f) {
    unsigned u = __float_as_uint(f);
    u += 0x7fffu + ((u >> 16) & 1u);   // round-to-nearest-even (no NaN in data)
    return (ushort_t)(u >> 16);
}

// ---------------------------------------------------------------------------
// Kernel 1: eH[k][d] = bf16(cb[k][d]); B[k] = ||e_k||^2 in numpy pairwise
// order: pw(x,256)=pw(x,128)+pw(x+128,128); pw(x,128): 8 accums x 16 strided
// adds, then ((r0+r1)+(r2+r3))+((r4+r5)+(r6+r7)).
__global__ void vq_prep(const float* __restrict__ cb, float* __restrict__ ws) {
    const int k = blockIdx.x;
    const int t = threadIdx.x;  // 0..255 == d
    ushort_t* eh = (ushort_t*)ws;
    eh[(size_t)k * D + t] = bf16_rne(cb[k * D + t]);
    __shared__ float r16[16];
    if (t < 16) {
#pragma clang fp contract(off)
        const float* x = cb + k * D + (t >> 3) * 128;
        const int j = t & 7;
        float v = x[j];
        float r = v * v;
        for (int i = 1; i < 16; ++i) {
            float w = x[8 * i + j];
            r += w * w;
        }
        r16[t] = r;
    }
    __syncthreads();
    if (t == 0) {
#pragma clang fp contract(off)
        float lo = ((r16[0] + r16[1]) + (r16[2] + r16[3])) +
                   ((r16[4] + r16[5]) + (r16[6] + r16[7]));
        float hi = ((r16[8] + r16[9]) + (r16[10] + r16[11])) +
                   ((r16[12] + r16[13]) + (r16[14] + r16[15]));
        ws[WS_B + k] = lo + hi;
    }
}

// ---------------------------------------------------------------------------
// Kernel 2: argmin. Per 32-row block (~24 KB LDS):
//   ONE fused pass over z: numpy-pairwise A chains + bf16-hi -> LDS;
//   MFMA approx scores (4 waves x 128 codes x 32 rows, hi term only);
//   per-row approx min + candidate collection (<= min+EPS);
//   exact fp32-chain re-score of candidates (sparse global z reads);
//   index write (float to out, int to ws for the gather kernel).
__global__ __launch_bounds__(256, 4) void vq_argmin2(
    const float* __restrict__ z_e, const float* __restrict__ cb,
    const ushort_t* __restrict__ eh, const float* __restrict__ Bv,
    int* __restrict__ wsidx, float* __restrict__ out) {
    __shared__ __align__(16) ushort_t zh[32][264];    // 16.9 KB bf16 hi, padded
    __shared__ float lds_B[K];                        // 2 KB ||e_k||^2
    __shared__ float scr[32][17];                     // 2.2 KB pairwise accums
    __shared__ int cand[32][MAXC];                    // 2 KB candidate codes
    __shared__ float lds_A[32];
    __shared__ float wmin[4][32];
    __shared__ float rmin[32];
    __shared__ int cnt[32];

    const int t = threadIdx.x;
    const int row0 = blockIdx.x * 32;
    const int b = row0 >> 10;
    const int hw0 = row0 & 1023;
    const float* zbase = z_e + (size_t)b * CHW + hw0;

    // ---- B staging
    lds_B[t] = Bv[t];
    lds_B[t + 256] = Bv[t + 256];

    // ---- fused: A pairwise chains + bf16-hi conversion (single z read).
    // thread (row=t&31, q=t>>5): half=q>>2, j0=(q&3)*2; channels cbase+8i+j0{,+1}.
    {
        const int row = t & 31;
        const int q = t >> 5;
        const int half = q >> 2;
        const int j0 = (q & 3) * 2;
        const int cbase = half * 128;
        const float* zp = zbase + row;
        float r0, r1;
        {
#pragma clang fp contract(off)
            const int c0 = cbase + j0;
            float w0 = zp[(size_t)c0 * HW];
            float w1 = zp[(size_t)(c0 + 1) * HW];
            r0 = w0 * w0;
            r1 = w1 * w1;
            *reinterpret_cast<unsigned*>(&zh[row][c0]) =
                (unsigned)bf16_rne(w0) | ((unsigned)bf16_rne(w1) << 16);
            for (int i = 1; i < 16; ++i) {
                const int c = cbase + 8 * i + j0;
                float u0 = zp[(size_t)c * HW];
                float u1 = zp[(size_t)(c + 1) * HW];
                r0 += u0 * u0;
                r1 += u1 * u1;
                *reinterpret_cast<unsigned*>(&zh[row][c]) =
                    (unsigned)bf16_rne(u0) | ((unsigned)bf16_rne(u1) << 16);
            }
        }
        scr[row][half * 8 + j0] = r0;
        scr[row][half * 8 + j0 + 1] = r1;
    }
    __syncthreads();
    if (t < 32) {
#pragma clang fp contract(off)
        const float* r = scr[t];
        float lo = ((r[0] + r[1]) + (r[2] + r[3])) + ((r[4] + r[5]) + (r[6] + r[7]));
        float hi = ((r[8] + r[9]) + (r[10] + r[11])) + ((r[12] + r[13]) + (r[14] + r[15]));
        lds_A[t] = lo + hi;
    }

    // ---- MFMA main loop: wave w owns codes [w*128, w*128+128), all 32 rows.
    // A = E (codes = M), B = Z-hi (rows = N). hi term only.
    // C frag (m89-verified): col = lane&15 = z-row; row = 4*(lane>>4)+reg = code.
    const int lane = t & 63;
    const int w = t >> 6;
    const int wc0 = w * 128;
    const int l15 = lane & 15;
    const int kg = lane >> 4;

    float4v acc[8][2];
#pragma unroll
    for (int c = 0; c < 8; ++c)
#pragma unroll
        for (int rt = 0; rt < 2; ++rt) acc[c][rt] = (float4v)0.f;

    const ushort_t* ehp = eh + (size_t)(wc0 + l15) * D + 8 * kg;

#pragma unroll 4
    for (int d0 = 0; d0 < D; d0 += 32) {
        const short8v bh0 = *reinterpret_cast<const short8v*>(&zh[l15][d0 + 8 * kg]);
        const short8v bh1 = *reinterpret_cast<const short8v*>(&zh[16 + l15][d0 + 8 * kg]);
#pragma unroll
        for (int c = 0; c < 8; ++c) {
            const short8v a = *reinterpret_cast<const short8v*>(ehp + c * 16 * D + d0);
            acc[c][0] = __builtin_amdgcn_mfma_f32_16x16x32_bf16(a, bh0, acc[c][0], 0, 0, 0);
            acc[c][1] = __builtin_amdgcn_mfma_f32_16x16x32_bf16(a, bh1, acc[c][1], 0, 0, 0);
        }
    }
    __syncthreads();  // lds_A ready for all; zh stable until cand phase done

    // ---- approx scores + per-row min
    float lmin0 = 3.0e38f, lmin1 = 3.0e38f;
#pragma unroll
    for (int c = 0; c < 8; ++c)
#pragma unroll
        for (int rt = 0; rt < 2; ++rt)
#pragma unroll
            for (int r = 0; r < 4; ++r) {
                const int code = wc0 + 16 * c + 4 * kg + r;
                const int row = rt * 16 + l15;
                float s = (lds_A[row] + lds_B[code]) - 2.0f * acc[c][rt][r];
                acc[c][rt][r] = s;
                if (rt == 0) lmin0 = fminf(lmin0, s);
                else lmin1 = fminf(lmin1, s);
            }
    lmin0 = fminf(lmin0, __shfl_xor(lmin0, 16));
    lmin0 = fminf(lmin0, __shfl_xor(lmin0, 32));
    lmin1 = fminf(lmin1, __shfl_xor(lmin1, 16));
    lmin1 = fminf(lmin1, __shfl_xor(lmin1, 32));
    if (lane < 16) {
        wmin[w][l15] = lmin0;
        wmin[w][16 + l15] = lmin1;
    }
    __syncthreads();
    if (t < 32) {
        rmin[t] = fminf(fminf(wmin[0][t], wmin[1][t]), fminf(wmin[2][t], wmin[3][t]));
        cnt[t] = 0;
    }
    __syncthreads();

    // ---- candidate collection (any possible exact winner is within EPS)
#pragma unroll
    for (int c = 0; c < 8; ++c)
#pragma unroll
        for (int rt = 0; rt < 2; ++rt) {
            const int row = rt * 16 + l15;
            const float thr = rmin[row] + EPS_CAND;
#pragma unroll
            for (int r = 0; r < 4; ++r) {
                if (acc[c][rt][r] <= thr) {
                    const int code = wc0 + 16 * c + 4 * kg + r;
                    int slot = atomicAdd(&cnt[row], 1);
                    if (slot < MAXC) cand[row][slot] = code;
                }
            }
        }
    __syncthreads();

    // ---- exact pass: bitwise numpy-fp32 chain for rows with >=2 candidates.
    // zh buffer is dead now; alias reduction arrays onto it.
    float* ed = reinterpret_cast<float*>(&zh[0][0]);  // [8][32]
    int* ek = reinterpret_cast<int*>(ed + 256);       // [8][32]
    {
        const int row = t & 31;
        const int ct = t >> 5;  // 0..7 candidate-threads per row
        const float* zp = zbase + row;
        const int n = cnt[row];
        float bd = 3.0e38f;
        int bk = 0x7fffffff;
        if (n == 1) {
            if (ct == 0) {
                bd = -3.0e38f;
                bk = cand[row][0];
            }
        } else {
            const bool full = (n > MAXC);  // overflow: exact-scan all codes
            const int lim = full ? K : n;
            for (int s = ct; s < lim; s += 8) {
                const int k = full ? s : cand[row][s];
                const float* ep = cb + (size_t)k * D;
                float a = 0.f;
#pragma unroll 8
                for (int c = 0; c < D; ++c) a = fmaf(zp[(size_t)c * HW], ep[c], a);
                float dv;
                {
#pragma clang fp contract(off)
                    float t1 = lds_A[row] + lds_B[k];
                    dv = t1 - 2.0f * a;
                }
                if (dv < bd || (dv == bd && k < bk)) {
                    bd = dv;
                    bk = k;
                }
            }
        }
        ed[t] = bd;
        ek[t] = bk;
    }
    __syncthreads();
    if (t < 32) {
        float bd = ed[t];
        int bk = ek[t];
#pragma unroll
        for (int q = 1; q < 8; ++q) {
            float od = ed[q * 32 + t];
            int ok = ek[q * 32 + t];
            if (od < bd || (od == bd && ok < bk)) {
                bd = od;
                bk = ok;
            }
        }
        wsidx[row0 + t] = bk;
        out[IDX_OFF + row0 + t] = (float)bk;
    }
}

// ---------------------------------------------------------------------------
// Kernel 3: streaming gather / straight-through write / loss partials.
// Block: 256 threads = 4 waves; block covers (image b, 256 hw, 32 channels).
// Thread: 4 consecutive hw (float4), 8 channels; codebook rows are 4
// sequential L1-friendly streams. Zero LDS except 16 B -> max occupancy.
__global__ __launch_bounds__(256, 8) void vq_gather2(
    const float* __restrict__ z_e, const float* __restrict__ cb,
    const int* __restrict__ wsidx, float* __restrict__ part,
    float* __restrict__ out) {
    __shared__ float wpart[4];
    const int t = threadIdx.x;
    const int blk = blockIdx.x;
    const int cg = blk & 7;        // channel group (32 c)
    const int q = (blk >> 3) & 3;  // hw quarter (256 hw)
    const int b = blk >> 5;        // image
    const int lane = t & 63;
    const int csub = t >> 6;       // 0..3 (wave id)
    const int hw = q * 256 + lane * 4;

    const int4 kk = *reinterpret_cast<const int4*>(&wsidx[b * HW + hw]);
    const float* e0 = cb + (size_t)kk.x * D;
    const float* e1 = cb + (size_t)kk.y * D;
    const float* e2 = cb + (size_t)kk.z * D;
    const float* e3 = cb + (size_t)kk.w * D;
    const size_t zoff = (size_t)b * CHW + hw;

    float accum = 0.f;
#pragma unroll 2
    for (int i = 0; i < 8; ++i) {
        const int c = cg * 32 + csub * 8 + i;
        const size_t off = zoff + (size_t)c * HW;
        const float4 z4 = *reinterpret_cast<const float4*>(&z_e[off]);
        const float ex = e0[c], ey = e1[c], ez = e2[c], ew = e3[c];
        float4 o4;
        o4.x = z4.x + (ex - z4.x);
        o4.y = z4.y + (ey - z4.y);
        o4.z = z4.z + (ez - z4.z);
        o4.w = z4.w + (ew - z4.w);
        *reinterpret_cast<float4*>(&out[off]) = o4;
        accum = fmaf(z4.x - ex, z4.x - ex, accum);
        accum = fmaf(z4.y - ey, z4.y - ey, accum);
        accum = fmaf(z4.z - ez, z4.z - ez, accum);
        accum = fmaf(z4.w - ew, z4.w - ew, accum);
    }
#pragma unroll
    for (int m = 1; m < 64; m <<= 1) accum += __shfl_xor(accum, m);
    if (lane == 0) wpart[csub] = accum;
    __syncthreads();
    if (t == 0) part[blk] = (wpart[0] + wpart[1]) + (wpart[2] + wpart[3]);
}

// ---------------------------------------------------------------------------
// Kernel 4: final loss reduction (2048 partials, fp64, deterministic).
__global__ void vq_finish(const float* __restrict__ part, float* __restrict__ out) {
    const int t = threadIdx.x;  // 256 threads
    double s = 0.0;
#pragma unroll
    for (int i = 0; i < 8; ++i) s += (double)part[t + 256 * i];
#pragma unroll
    for (int m = 1; m < 64; m <<= 1) s += __shfl_xor(s, m);
    __shared__ double wsum[4];
    if ((t & 63) == 0) wsum[t >> 6] = s;
    __syncthreads();
    if (t == 0) {
        double mean = (wsum[0] + wsum[1] + wsum[2] + wsum[3]) / (double)ZQ_SIZE;
        out[LOSS0_OFF] = (float)mean;
        out[LOSS1_OFF] = (float)mean;
    }
}

// ---------------------------------------------------------------------------
extern "C" void kernel_launch(void* const* d_in, const int* in_sizes, int n_in,
                              void* d_out, int out_size, void* d_ws, size_t ws_size,
                              hipStream_t stream) {
    const float* z_e = (const float*)d_in[0];
    const float* cb = (const float*)d_in[1];
    float* out = (float*)d_out;
    float* ws = (float*)d_ws;

    const ushort_t* eh = (const ushort_t*)ws;
    float* Bv = ws + WS_B;
    int* wsidx = (int*)(ws + WS_KIDX);
    float* part = ws + WS_PART;

    vq_prep<<<K, D, 0, stream>>>(cb, ws);
    vq_argmin2<<<NBLK_A, 256, 0, stream>>>(z_e, cb, eh, Bv, wsidx, out);
    vq_gather2<<<NBLK_G, 256, 0, stream>>>(z_e, cb, wsidx, part, out);
    vq_finish<<<1, 256, 0, stream>>>(part, out);
}